// Round 1
// baseline (2606.147 us; speedup 1.0000x reference)
//
#include <hip/hip_runtime.h>
#include <math.h>

#define T_TOK 8192
#define HD    2048
#define ID    4096
#define NE    8
#define SROWS 16512   // 16384 + 128 pad rows

typedef __bf16 bf16x8 __attribute__((ext_vector_type(8)));
typedef float  f32x4  __attribute__((ext_vector_type(4)));

__device__ __forceinline__ unsigned short f2bf(float f) {
  unsigned int u = __builtin_bit_cast(unsigned int, f);
  u += 0x7FFFu + ((u >> 16) & 1u);   // round-to-nearest-even
  return (unsigned short)(u >> 16);
}

__device__ __forceinline__ void gl_lds16(const void* gptr, void* lptr) {
  __builtin_amdgcn_global_load_lds(
      (const __attribute__((address_space(1))) unsigned int*)gptr,
      (__attribute__((address_space(3))) unsigned int*)lptr, 16, 0, 0);
}

// ---------------- fp32 -> bf16 elementwise (for x) ----------------
__global__ __launch_bounds__(256) void cvt_x_kernel(const float* __restrict__ in,
                                                    unsigned short* __restrict__ out) {
  const int n4 = (T_TOK * HD) / 4;
  for (int i = blockIdx.x * blockDim.x + threadIdx.x; i < n4; i += gridDim.x * blockDim.x) {
    float4 v = ((const float4*)in)[i];
    ushort4 o;
    o.x = f2bf(v.x); o.y = f2bf(v.y); o.z = f2bf(v.z); o.w = f2bf(v.w);
    ((ushort4*)out)[i] = o;
  }
}

// ------- transpose+convert: in [E][K][N] f32 -> out [E][N][K] bf16 -------
__global__ __launch_bounds__(256) void transpose_cvt_kernel(const float* __restrict__ in,
                                                            unsigned short* __restrict__ out,
                                                            int K, int N) {
  const int e = blockIdx.z;
  const float* ip = in + (size_t)e * K * N;
  unsigned short* op = out + (size_t)e * K * N;
  const int n0 = blockIdx.x * 64;
  const int k0 = blockIdx.y * 64;
  __shared__ unsigned short tile[64][65];
  const int t = threadIdx.x;
  {
    const int fr = t >> 4, fc = t & 15;
#pragma unroll
    for (int p = 0; p < 4; p++) {
      const int kl = p * 16 + fr;
      float4 v = *(const float4*)(ip + (size_t)(k0 + kl) * N + n0 + fc * 4);
      tile[fc * 4 + 0][kl] = f2bf(v.x);
      tile[fc * 4 + 1][kl] = f2bf(v.y);
      tile[fc * 4 + 2][kl] = f2bf(v.z);
      tile[fc * 4 + 3][kl] = f2bf(v.w);
    }
  }
  __syncthreads();
  {
    const int nr = t >> 5, kc = t & 31;
#pragma unroll
    for (int p = 0; p < 8; p++) {
      const int nl = p * 8 + nr;
      unsigned int val = (unsigned int)tile[nl][kc * 2] |
                         ((unsigned int)tile[nl][kc * 2 + 1] << 16);
      *(unsigned int*)(op + (size_t)(n0 + nl) * K + k0 + kc * 2) = val;
    }
  }
}

// ---------------- router: fp64 logits, softmax, top-2 ----------------
__global__ __launch_bounds__(256) void router_kernel(const float* __restrict__ x,
                                                     const float* __restrict__ wr,
                                                     int* __restrict__ counts,
                                                     int* __restrict__ rec_e,
                                                     float* __restrict__ rec_w) {
  const int w = threadIdx.x >> 6, lane = threadIdx.x & 63;
  const int t = blockIdx.x * 4 + w;
  const float* xr = x + (size_t)t * HD;
  double acc[NE];
#pragma unroll
  for (int e = 0; e < NE; e++) acc[e] = 0.0;
  for (int h = lane; h < HD; h += 64) {
    float xv = xr[h];
    const float4* w4 = (const float4*)(wr + h * NE);
    float4 wa = w4[0], wb = w4[1];
    double xd = (double)xv;
    acc[0] += xd * (double)wa.x; acc[1] += xd * (double)wa.y;
    acc[2] += xd * (double)wa.z; acc[3] += xd * (double)wa.w;
    acc[4] += xd * (double)wb.x; acc[5] += xd * (double)wb.y;
    acc[6] += xd * (double)wb.z; acc[7] += xd * (double)wb.w;
  }
#pragma unroll
  for (int off = 32; off > 0; off >>= 1) {
#pragma unroll
    for (int e = 0; e < NE; e++) acc[e] += __shfl_down(acc[e], off, 64);
  }
  if (lane == 0) {
    double mx = acc[0];
#pragma unroll
    for (int e = 1; e < NE; e++) mx = fmax(mx, acc[e]);
    double p[NE], ssum = 0.0;
#pragma unroll
    for (int e = 0; e < NE; e++) { p[e] = exp(acc[e] - mx); ssum += p[e]; }
    int i0 = 0;
#pragma unroll
    for (int e = 1; e < NE; e++) if (p[e] > p[i0]) i0 = e;
    int i1 = (i0 == 0) ? 1 : 0;
#pragma unroll
    for (int e = 0; e < NE; e++) if (e != i0 && p[e] > p[i1]) i1 = e;
    rec_e[2 * t]     = i0;
    rec_e[2 * t + 1] = i1;
    rec_w[2 * t]     = (float)(p[i0] / ssum);
    rec_w[2 * t + 1] = (float)(p[i1] / ssum);
    atomicAdd(&counts[i0], 1);
    atomicAdd(&counts[i1], 1);
  }
}

__global__ void offsets_kernel(const int* __restrict__ counts,
                               int* __restrict__ soff, int* __restrict__ fill) {
  if (threadIdx.x == 0 && blockIdx.x == 0) {
    int s = 0;
    for (int e = 0; e < NE; e++) { soff[e] = s; s += counts[e]; fill[e] = 0; }
    soff[NE] = s;
  }
}

__global__ __launch_bounds__(256) void scatter_kernel(const int* __restrict__ rec_e,
                                                      const float* __restrict__ rec_w,
                                                      const int* __restrict__ soff,
                                                      int* __restrict__ fill,
                                                      int* __restrict__ list,
                                                      float* __restrict__ wts) {
  int t = blockIdx.x * blockDim.x + threadIdx.x;
  if (t >= T_TOK) return;
#pragma unroll
  for (int s = 0; s < 2; s++) {
    int e = rec_e[2 * t + s];
    int pos = atomicAdd(&fill[e], 1);
    int slot = soff[e] + pos;
    list[slot] = t;
    wts[slot] = rec_w[2 * t + s];
  }
}

// ---------------- GEMM1: s = silu(0.5 * x@Wg) * (x@Wu), bf16 MFMA ----------------
// grid: (64 m-tiles, 32 n-tiles, 8 experts), block 256 (4 waves, 2x2 of 64x64)
__global__ __launch_bounds__(256, 2) void gemm1_kernel(
    const unsigned short* __restrict__ xb,    // [T_TOK][HD] bf16
    const unsigned short* __restrict__ wgT,   // [E][ID][HD] bf16 (transposed)
    const unsigned short* __restrict__ wuT,   // [E][ID][HD]
    const int* __restrict__ counts, const int* __restrict__ soff,
    const int* __restrict__ list,
    unsigned short* __restrict__ s_out)       // [SROWS][ID] bf16
{
  const int e = blockIdx.z;
  const int cnt = counts[e];
  const int m0 = blockIdx.x * 128;
  if (m0 >= cnt) return;
  const int n0 = blockIdx.y * 128;
  const int so = soff[e];

  const int tid = threadIdx.x;
  const int lane = tid & 63;
  const int w = tid >> 6;

  __shared__ unsigned short As[128 * 64];
  __shared__ unsigned short Bgs[128 * 64];
  __shared__ unsigned short Bus[128 * 64];

  const int rsub = lane >> 3;                              // 0..7: row within 8-row chunk
  const int kp   = ((lane & 7) ^ rsub) * 8;                // XOR-swizzled k-chunk (elems)

  // staging source bases (element offsets)
  size_t abase[4], bbase[4];
  int lo[4];
#pragma unroll
  for (int i = 0; i < 4; i++) {
    int r = (i * 4 + w) * 8 + rsub;
    int m = m0 + r; m = m < cnt ? m : cnt - 1;
    int tok = list[so + m];
    abase[i] = (size_t)tok * HD + kp;
    bbase[i] = (size_t)(n0 + r) * HD + kp;
    lo[i] = (i * 4 + w) * 512 + lane * 8;                  // LDS dest (elems)
  }
  const unsigned short* bg = wgT + (size_t)e * ID * HD;
  const unsigned short* bu = wuT + (size_t)e * ID * HD;

  f32x4 accg[4][4], accu[4][4];
#pragma unroll
  for (int mi = 0; mi < 4; mi++)
#pragma unroll
    for (int ni = 0; ni < 4; ni++) {
      accg[mi][ni] = (f32x4)0.0f;
      accu[mi][ni] = (f32x4)0.0f;
    }

  const int wm = (w >> 1) * 64;
  const int wn = (w & 1) * 64;
  const int frow = lane & 15;
  const int quad = lane >> 4;

  for (int k0 = 0; k0 < HD; k0 += 64) {
    __syncthreads();
#pragma unroll
    for (int i = 0; i < 4; i++) {
      gl_lds16(xb + abase[i] + k0, As + lo[i]);
      gl_lds16(bg + bbase[i] + k0, Bgs + lo[i]);
      gl_lds16(bu + bbase[i] + k0, Bus + lo[i]);
    }
    __syncthreads();
#pragma unroll
    for (int ks = 0; ks < 2; ks++) {
      const int ph = ((ks * 4 + quad) ^ (frow & 7)) * 8;   // swizzled read offset
      bf16x8 af[4], gf[4], uf[4];
#pragma unroll
      for (int mi = 0; mi < 4; mi++)
        af[mi] = *(const bf16x8*)(As + (wm + mi * 16 + frow) * 64 + ph);
#pragma unroll
      for (int ni = 0; ni < 4; ni++) {
        gf[ni] = *(const bf16x8*)(Bgs + (wn + ni * 16 + frow) * 64 + ph);
        uf[ni] = *(const bf16x8*)(Bus + (wn + ni * 16 + frow) * 64 + ph);
      }
#pragma unroll
      for (int mi = 0; mi < 4; mi++)
#pragma unroll
        for (int ni = 0; ni < 4; ni++) {
          accg[mi][ni] = __builtin_amdgcn_mfma_f32_16x16x32_bf16(af[mi], gf[ni], accg[mi][ni], 0, 0, 0);
          accu[mi][ni] = __builtin_amdgcn_mfma_f32_16x16x32_bf16(af[mi], uf[ni], accu[mi][ni], 0, 0, 0);
        }
    }
  }

  // epilogue: silu(g*0.5)*u -> bf16
  const int colbase = n0 + wn + frow;
#pragma unroll
  for (int mi = 0; mi < 4; mi++) {
#pragma unroll
    for (int r = 0; r < 4; r++) {
      const int m = m0 + wm + mi * 16 + quad * 4 + r;
      if (m < cnt) {
        unsigned short* dst = s_out + (size_t)(so + m) * ID + colbase;
#pragma unroll
        for (int ni = 0; ni < 4; ni++) {
          float gv = accg[mi][ni][r] * 0.5f;
          float uv = accu[mi][ni][r];
          float sv = (gv / (1.0f + __expf(-gv))) * uv;
          dst[ni * 16] = f2bf(sv);
        }
      }
    }
  }
}

// ---------------- GEMM2: out[tok] += w * 0.25 * (s @ Wd) ----------------
// grid: (64 m-tiles, 16 n-tiles, 8 experts), block 256
__global__ __launch_bounds__(256, 2) void gemm2_kernel(
    const unsigned short* __restrict__ s_in,  // [SROWS][ID] bf16
    const unsigned short* __restrict__ wdT,   // [E][HD][ID] bf16 (transposed)
    const int* __restrict__ counts, const int* __restrict__ soff,
    const int* __restrict__ list, const float* __restrict__ wts,
    float* __restrict__ out)                  // [T_TOK][HD] fp32
{
  const int e = blockIdx.z;
  const int cnt = counts[e];
  const int m0 = blockIdx.x * 128;
  if (m0 >= cnt) return;
  const int n0 = blockIdx.y * 128;
  const int so = soff[e];

  const int tid = threadIdx.x;
  const int lane = tid & 63;
  const int w = tid >> 6;

  __shared__ unsigned short As[128 * 64];
  __shared__ unsigned short Bs[128 * 64];
  __shared__ int   tokLDS[128];
  __shared__ float wLDS[128];

  const int rsub = lane >> 3;
  const int kp   = ((lane & 7) ^ rsub) * 8;

  size_t abase[4], bbase[4];
  int lo[4];
#pragma unroll
  for (int i = 0; i < 4; i++) {
    int r = (i * 4 + w) * 8 + rsub;
    abase[i] = (size_t)(so + m0 + r) * ID + kp;            // padded s buffer: no clamp
    bbase[i] = (size_t)(n0 + r) * ID + kp;
    lo[i] = (i * 4 + w) * 512 + lane * 8;
  }
  const unsigned short* bd = wdT + (size_t)e * HD * ID;

  f32x4 acc[4][4];
#pragma unroll
  for (int mi = 0; mi < 4; mi++)
#pragma unroll
    for (int ni = 0; ni < 4; ni++) acc[mi][ni] = (f32x4)0.0f;

  const int wm = (w >> 1) * 64;
  const int wn = (w & 1) * 64;
  const int frow = lane & 15;
  const int quad = lane >> 4;

  for (int k0 = 0; k0 < ID; k0 += 64) {
    __syncthreads();
#pragma unroll
    for (int i = 0; i < 4; i++) {
      gl_lds16(s_in + abase[i] + k0, As + lo[i]);
      gl_lds16(bd + bbase[i] + k0, Bs + lo[i]);
    }
    __syncthreads();
#pragma unroll
    for (int ks = 0; ks < 2; ks++) {
      const int ph = ((ks * 4 + quad) ^ (frow & 7)) * 8;
      bf16x8 af[4], bf[4];
#pragma unroll
      for (int mi = 0; mi < 4; mi++)
        af[mi] = *(const bf16x8*)(As + (wm + mi * 16 + frow) * 64 + ph);
#pragma unroll
      for (int ni = 0; ni < 4; ni++)
        bf[ni] = *(const bf16x8*)(Bs + (wn + ni * 16 + frow) * 64 + ph);
#pragma unroll
      for (int mi = 0; mi < 4; mi++)
#pragma unroll
        for (int ni = 0; ni < 4; ni++)
          acc[mi][ni] = __builtin_amdgcn_mfma_f32_16x16x32_bf16(af[mi], bf[ni], acc[mi][ni], 0, 0, 0);
    }
  }

  // stage token ids + combine weights for this m-tile
  if (tid < 128) {
    int m = m0 + tid; int mm = m < cnt ? m : cnt - 1;
    tokLDS[tid] = list[so + mm];
    wLDS[tid] = wts[so + mm];
  }
  __syncthreads();

  const int colbase = n0 + wn + frow;
#pragma unroll
  for (int mi = 0; mi < 4; mi++) {
#pragma unroll
    for (int r = 0; r < 4; r++) {
      const int ml = wm + mi * 16 + quad * 4 + r;
      const int m = m0 + ml;
      if (m < cnt) {
        const int tok = tokLDS[ml];
        const float wv = wLDS[ml] * 0.25f;
        float* dst = out + (size_t)tok * HD + colbase;
#pragma unroll
        for (int ni = 0; ni < 4; ni++)
          atomicAdd(&dst[ni * 16], acc[mi][ni][r] * wv);
      }
    }
  }
}

// ---------------- workspace layout ----------------
#define OFF_XB   ((size_t)0)
#define OFF_W1   (OFF_XB + (size_t)T_TOK * HD * 2)
#define OFF_W2   (OFF_W1 + (size_t)NE * ID * HD * 2)
#define OFF_S    (OFF_W2 + (size_t)NE * ID * HD * 2)
#define OFF_RECE (OFF_S + (size_t)SROWS * ID * 2)
#define OFF_RECW (OFF_RECE + (size_t)T_TOK * 2 * 4)
#define OFF_LIST (OFF_RECW + (size_t)T_TOK * 2 * 4)
#define OFF_WTS  (OFF_LIST + (size_t)SROWS * 4)
#define OFF_CTRL (OFF_WTS + (size_t)SROWS * 4)
#define WS_NEED  (OFF_CTRL + 256)

extern "C" void kernel_launch(void* const* d_in, const int* in_sizes, int n_in,
                              void* d_out, int out_size, void* d_ws, size_t ws_size,
                              hipStream_t stream) {
  const float* x  = (const float*)d_in[0];
  const float* wr = (const float*)d_in[1];
  const float* wg = (const float*)d_in[2];
  const float* wu = (const float*)d_in[3];
  const float* wd = (const float*)d_in[4];
  float* out = (float*)d_out;

  if (ws_size < WS_NEED) return;  // fails validation loudly rather than corrupting

  char* ws = (char*)d_ws;
  unsigned short* xb   = (unsigned short*)(ws + OFF_XB);
  unsigned short* W1   = (unsigned short*)(ws + OFF_W1);   // wgT, then wdT
  unsigned short* W2   = (unsigned short*)(ws + OFF_W2);   // wuT
  unsigned short* sbuf = (unsigned short*)(ws + OFF_S);
  int*   rec_e = (int*)(ws + OFF_RECE);
  float* rec_w = (float*)(ws + OFF_RECW);
  int*   list  = (int*)(ws + OFF_LIST);
  float* wts   = (float*)(ws + OFF_WTS);
  int*   ctrl  = (int*)(ws + OFF_CTRL);
  int* counts = ctrl;
  int* fill   = ctrl + 8;
  int* soff   = ctrl + 16;

  hipMemsetAsync(ctrl, 0, 128, stream);
  hipMemsetAsync(out, 0, (size_t)T_TOK * HD * 4, stream);

  cvt_x_kernel<<<4096, 256, 0, stream>>>(x, xb);
  transpose_cvt_kernel<<<dim3(ID / 64, HD / 64, NE), 256, 0, stream>>>(wg, W1, HD, ID);
  transpose_cvt_kernel<<<dim3(ID / 64, HD / 64, NE), 256, 0, stream>>>(wu, W2, HD, ID);
  router_kernel<<<T_TOK / 4, 256, 0, stream>>>(x, wr, counts, rec_e, rec_w);
  offsets_kernel<<<1, 64, 0, stream>>>(counts, soff, fill);
  scatter_kernel<<<T_TOK / 256, 256, 0, stream>>>(rec_e, rec_w, soff, fill, list, wts);
  gemm1_kernel<<<dim3(64, ID / 128, NE), 256, 0, stream>>>(xb, W1, W2, counts, soff, list, sbuf);
  transpose_cvt_kernel<<<dim3(HD / 64, ID / 64, NE), 256, 0, stream>>>(wd, W1, ID, HD);
  gemm2_kernel<<<dim3(64, HD / 128, NE), 256, 0, stream>>>(sbuf, W1, counts, soff, list, wts, out);
}

// Round 2
// 2058.785 us; speedup vs baseline: 1.2659x; 1.2659x over previous
//
#include <hip/hip_runtime.h>
#include <math.h>

#define T_TOK 8192
#define HD    2048
#define ID    4096
#define NE    8
#define SROWS 16512   // 16384 + 128 pad rows
#define NT1   (ID / 64)     // 64 n-tiles for gemm1 (n-extent 64)
#define NT2   (HD / 128)    // 16 n-tiles for gemm2
#define MAXMT (T_TOK * 2 / 128 + NE)   // 135 worst-case m-tiles
#define GRID1 (MAXMT * NT1)
#define GRID2 (MAXMT * NT2)

typedef __bf16 bf16x8 __attribute__((ext_vector_type(8)));
typedef float  f32x4  __attribute__((ext_vector_type(4)));

__device__ __forceinline__ unsigned short f2bf(float f) {
  unsigned int u = __builtin_bit_cast(unsigned int, f);
  u += 0x7FFFu + ((u >> 16) & 1u);   // round-to-nearest-even
  return (unsigned short)(u >> 16);
}

__device__ __forceinline__ void gl_lds16(const void* gptr, void* lptr) {
  __builtin_amdgcn_global_load_lds(
      (const __attribute__((address_space(1))) unsigned int*)gptr,
      (__attribute__((address_space(3))) unsigned int*)lptr, 16, 0, 0);
}

// ------- transpose+convert: in [E][K][N] f32 -> out [E][N][K] bf16 -------
__global__ __launch_bounds__(256) void transpose_cvt_kernel(const float* __restrict__ in,
                                                            unsigned short* __restrict__ out,
                                                            int K, int N) {
  const int e = blockIdx.z;
  const float* ip = in + (size_t)e * K * N;
  unsigned short* op = out + (size_t)e * K * N;
  const int n0 = blockIdx.x * 64;
  const int k0 = blockIdx.y * 64;
  __shared__ unsigned short tile[64][65];
  const int t = threadIdx.x;
  {
    const int fr = t >> 4, fc = t & 15;
#pragma unroll
    for (int p = 0; p < 4; p++) {
      const int kl = p * 16 + fr;
      float4 v = *(const float4*)(ip + (size_t)(k0 + kl) * N + n0 + fc * 4);
      tile[fc * 4 + 0][kl] = f2bf(v.x);
      tile[fc * 4 + 1][kl] = f2bf(v.y);
      tile[fc * 4 + 2][kl] = f2bf(v.z);
      tile[fc * 4 + 3][kl] = f2bf(v.w);
    }
  }
  __syncthreads();
  {
    const int nr = t >> 5, kc = t & 31;
#pragma unroll
    for (int p = 0; p < 8; p++) {
      const int nl = p * 8 + nr;
      unsigned int val = (unsigned int)tile[nl][kc * 2] |
                         ((unsigned int)tile[nl][kc * 2 + 1] << 16);
      *(unsigned int*)(op + (size_t)(n0 + nl) * K + k0 + kc * 2) = val;
    }
  }
}

// ------- router: fp64 logits, softmax, top-2; also emits x in bf16 -------
__global__ __launch_bounds__(256) void router_kernel(const float* __restrict__ x,
                                                     const float* __restrict__ wr,
                                                     int* __restrict__ counts,
                                                     int* __restrict__ rec_e,
                                                     float* __restrict__ rec_w,
                                                     unsigned short* __restrict__ xb) {
  const int w = threadIdx.x >> 6, lane = threadIdx.x & 63;
  const int t = blockIdx.x * 4 + w;
  const float* xr = x + (size_t)t * HD;
  unsigned short* xo = xb + (size_t)t * HD;
  double acc[NE];
#pragma unroll
  for (int e = 0; e < NE; e++) acc[e] = 0.0;
  for (int h = lane; h < HD; h += 64) {
    float xv = xr[h];
    xo[h] = f2bf(xv);              // fused fp32->bf16 conversion of x
    const float4* w4 = (const float4*)(wr + h * NE);
    float4 wa = w4[0], wb = w4[1];
    double xd = (double)xv;
    acc[0] += xd * (double)wa.x; acc[1] += xd * (double)wa.y;
    acc[2] += xd * (double)wa.z; acc[3] += xd * (double)wa.w;
    acc[4] += xd * (double)wb.x; acc[5] += xd * (double)wb.y;
    acc[6] += xd * (double)wb.z; acc[7] += xd * (double)wb.w;
  }
#pragma unroll
  for (int off = 32; off > 0; off >>= 1) {
#pragma unroll
    for (int e = 0; e < NE; e++) acc[e] += __shfl_down(acc[e], off, 64);
  }
  if (lane == 0) {
    double mx = acc[0];
#pragma unroll
    for (int e = 1; e < NE; e++) mx = fmax(mx, acc[e]);
    double p[NE], ssum = 0.0;
#pragma unroll
    for (int e = 0; e < NE; e++) { p[e] = exp(acc[e] - mx); ssum += p[e]; }
    int i0 = 0;
#pragma unroll
    for (int e = 1; e < NE; e++) if (p[e] > p[i0]) i0 = e;
    int i1 = (i0 == 0) ? 1 : 0;
#pragma unroll
    for (int e = 0; e < NE; e++) if (e != i0 && p[e] > p[i1]) i1 = e;
    rec_e[2 * t]     = i0;
    rec_e[2 * t + 1] = i1;
    rec_w[2 * t]     = (float)(p[i0] / ssum);
    rec_w[2 * t + 1] = (float)(p[i1] / ssum);
    atomicAdd(&counts[i0], 1);
    atomicAdd(&counts[i1], 1);
  }
}

// ctrl layout: [0..7] counts, [8..15] fill, [16..24] soff, [32..40] P1, [48..56] P2
__global__ void offsets_kernel(int* __restrict__ ctrl) {
  if (threadIdx.x == 0 && blockIdx.x == 0) {
    int s = 0;
    for (int e = 0; e < NE; e++) { ctrl[16 + e] = s; s += ctrl[e]; ctrl[8 + e] = 0; }
    ctrl[16 + NE] = s;
    int b1 = 0, b2 = 0;
    for (int e = 0; e < NE; e++) {
      ctrl[32 + e] = b1; ctrl[48 + e] = b2;
      int mt = (ctrl[e] + 127) >> 7;
      b1 += mt * NT1; b2 += mt * NT2;
    }
    ctrl[32 + NE] = b1; ctrl[48 + NE] = b2;
  }
}

__global__ __launch_bounds__(256) void scatter_kernel(const int* __restrict__ rec_e,
                                                      const float* __restrict__ rec_w,
                                                      int* __restrict__ ctrl,
                                                      int* __restrict__ list,
                                                      float* __restrict__ wts) {
  int t = blockIdx.x * blockDim.x + threadIdx.x;
  if (t >= T_TOK) return;
#pragma unroll
  for (int s = 0; s < 2; s++) {
    int e = rec_e[2 * t + s];
    int pos = atomicAdd(&ctrl[8 + e], 1);
    int slot = ctrl[16 + e] + pos;
    list[slot] = t;
    wts[slot] = rec_w[2 * t + s];
  }
}

// decode compact linear block index -> (expert, m-tile, n-tile); m innermost
__device__ __forceinline__ bool decode_tile(const int* ctrl, int pbase, int ntiles,
                                            int b, int& e, int& cnt, int& so,
                                            int& m0, int& n0, int next) {
  if (b >= ctrl[pbase + NE]) return false;
  e = 0;
#pragma unroll
  for (int i = 1; i < NE; i++) if (b >= ctrl[pbase + i]) e = i;
  cnt = ctrl[e];
  so  = ctrl[16 + e];
  const int mt = (cnt + 127) >> 7;
  const int local = b - ctrl[pbase + e];
  const int nt = local / mt;
  m0 = (local - nt * mt) * 128;
  n0 = nt * next;
  return true;
}

// -------- GEMM1: s = silu(0.5*x@Wg)*(x@Wu); 128x64 tile, g/u split across waves --------
__global__ __launch_bounds__(256, 3) void gemm1_kernel(
    const unsigned short* __restrict__ xb,    // [T_TOK][HD] bf16
    const unsigned short* __restrict__ wgT,   // [E][ID][HD] bf16
    const unsigned short* __restrict__ wuT,   // [E][ID][HD]
    const int* __restrict__ ctrl,
    const int* __restrict__ list,
    unsigned short* __restrict__ s_out)       // [SROWS][ID] bf16
{
  __shared__ char smem[33280];                // staging 32KB; epilogue dump 2*64*65*4B
  unsigned short* As  = (unsigned short*)smem;           // 128x64
  unsigned short* Bgs = (unsigned short*)(smem + 16384); // 64x64
  unsigned short* Bus = (unsigned short*)(smem + 24576); // 64x64

  int e, cnt, so, m0, n0;
  if (!decode_tile(ctrl, 32, NT1, blockIdx.x, e, cnt, so, m0, n0, 64)) return;

  const int tid = threadIdx.x;
  const int lane = tid & 63;
  const int w = tid >> 6;

  const int rsub = lane >> 3;
  const int kp   = ((lane & 7) ^ rsub) * 8;

  size_t abase[4]; int loA[4];
#pragma unroll
  for (int i = 0; i < 4; i++) {
    int r = (i * 4 + w) * 8 + rsub;
    int m = m0 + r; m = m < cnt ? m : cnt - 1;
    int tok = list[so + m];
    abase[i] = (size_t)tok * HD + kp;
    loA[i] = (i * 4 + w) * 512 + lane * 8;
  }
  size_t bbase[2]; int loB[2];
#pragma unroll
  for (int i = 0; i < 2; i++) {
    int r = (i * 4 + w) * 8 + rsub;
    bbase[i] = (size_t)(n0 + r) * HD + kp;
    loB[i] = (i * 4 + w) * 512 + lane * 8;
  }
  const unsigned short* bg = wgT + (size_t)e * ID * HD;
  const unsigned short* bu = wuT + (size_t)e * ID * HD;

  f32x4 acc[4][4];
#pragma unroll
  for (int mi = 0; mi < 4; mi++)
#pragma unroll
    for (int ni = 0; ni < 4; ni++) acc[mi][ni] = (f32x4)0.0f;

  const int wm = (w & 1) * 64;                        // waves 0,2 -> m 0-63; 1,3 -> 64-127
  const unsigned short* Bmy = (w & 2) ? Bus : Bgs;    // waves 0,1 gate; 2,3 up
  const int frow = lane & 15;
  const int quad = lane >> 4;

  for (int k0 = 0; k0 < HD; k0 += 64) {
    __syncthreads();
#pragma unroll
    for (int i = 0; i < 4; i++) gl_lds16(xb + abase[i] + k0, As + loA[i]);
#pragma unroll
    for (int i = 0; i < 2; i++) {
      gl_lds16(bg + bbase[i] + k0, Bgs + loB[i]);
      gl_lds16(bu + bbase[i] + k0, Bus + loB[i]);
    }
    __syncthreads();
#pragma unroll
    for (int ks = 0; ks < 2; ks++) {
      const int ph = ((ks * 4 + quad) ^ (frow & 7)) * 8;
      bf16x8 af[4], bf[4];
#pragma unroll
      for (int mi = 0; mi < 4; mi++)
        af[mi] = *(const bf16x8*)(As + (wm + mi * 16 + frow) * 64 + ph);
#pragma unroll
      for (int ni = 0; ni < 4; ni++)
        bf[ni] = *(const bf16x8*)(Bmy + (ni * 16 + frow) * 64 + ph);
#pragma unroll
      for (int mi = 0; mi < 4; mi++)
#pragma unroll
        for (int ni = 0; ni < 4; ni++)
          acc[mi][ni] = __builtin_amdgcn_mfma_f32_16x16x32_bf16(af[mi], bf[ni], acc[mi][ni], 0, 0, 0);
    }
  }

  // up-waves dump acc to LDS (stride 65 floats: conflict-free), gate-waves combine
  __syncthreads();
  float* dump = (float*)smem + (w & 1) * 4160;
  if (w & 2) {
#pragma unroll
    for (int mi = 0; mi < 4; mi++)
#pragma unroll
      for (int r = 0; r < 4; r++) {
        const int row = mi * 16 + quad * 4 + r;
#pragma unroll
        for (int ni = 0; ni < 4; ni++)
          dump[row * 65 + ni * 16 + frow] = acc[mi][ni][r];
      }
  }
  __syncthreads();
  if (!(w & 2)) {
#pragma unroll
    for (int mi = 0; mi < 4; mi++) {
#pragma unroll
      for (int r = 0; r < 4; r++) {
        const int row = mi * 16 + quad * 4 + r;
        const int m = m0 + wm + row;
        if (m < cnt) {
          unsigned short* dst = s_out + (size_t)(so + m) * ID + n0 + frow;
#pragma unroll
          for (int ni = 0; ni < 4; ni++) {
            float gv = acc[mi][ni][r] * 0.5f;
            float uv = dump[row * 65 + ni * 16 + frow];
            float sv = (gv / (1.0f + __expf(-gv))) * uv;
            dst[ni * 16] = f2bf(sv);
          }
        }
      }
    }
  }
}

// -------- GEMM2: out[tok] += w * 0.25 * (s @ Wd); 128x128 tile --------
__global__ __launch_bounds__(256, 3) void gemm2_kernel(
    const unsigned short* __restrict__ s_in,  // [SROWS][ID] bf16
    const unsigned short* __restrict__ wdT,   // [E][HD][ID] bf16
    const int* __restrict__ ctrl,
    const int* __restrict__ list, const float* __restrict__ wts,
    float* __restrict__ out)                  // [T_TOK][HD] fp32
{
  int e, cnt, so, m0, n0;
  if (!decode_tile(ctrl, 48, NT2, blockIdx.x, e, cnt, so, m0, n0, 128)) return;

  const int tid = threadIdx.x;
  const int lane = tid & 63;
  const int w = tid >> 6;

  __shared__ unsigned short As[128 * 64];
  __shared__ unsigned short Bs[128 * 64];
  __shared__ int   tokLDS[128];
  __shared__ float wLDS[128];

  const int rsub = lane >> 3;
  const int kp   = ((lane & 7) ^ rsub) * 8;

  size_t abase[4], bbase[4];
  int lo[4];
#pragma unroll
  for (int i = 0; i < 4; i++) {
    int r = (i * 4 + w) * 8 + rsub;
    abase[i] = (size_t)(so + m0 + r) * ID + kp;   // padded s buffer: no clamp needed
    bbase[i] = (size_t)(n0 + r) * ID + kp;
    lo[i] = (i * 4 + w) * 512 + lane * 8;
  }
  const unsigned short* bd = wdT + (size_t)e * HD * ID;

  f32x4 acc[4][4];
#pragma unroll
  for (int mi = 0; mi < 4; mi++)
#pragma unroll
    for (int ni = 0; ni < 4; ni++) acc[mi][ni] = (f32x4)0.0f;

  const int wm = (w >> 1) * 64;
  const int wn = (w & 1) * 64;
  const int frow = lane & 15;
  const int quad = lane >> 4;

  for (int k0 = 0; k0 < ID; k0 += 64) {
    __syncthreads();
#pragma unroll
    for (int i = 0; i < 4; i++) {
      gl_lds16(s_in + abase[i] + k0, As + lo[i]);
      gl_lds16(bd + bbase[i] + k0, Bs + lo[i]);
    }
    __syncthreads();
#pragma unroll
    for (int ks = 0; ks < 2; ks++) {
      const int ph = ((ks * 4 + quad) ^ (frow & 7)) * 8;
      bf16x8 af[4], bf[4];
#pragma unroll
      for (int mi = 0; mi < 4; mi++)
        af[mi] = *(const bf16x8*)(As + (wm + mi * 16 + frow) * 64 + ph);
#pragma unroll
      for (int ni = 0; ni < 4; ni++)
        bf[ni] = *(const bf16x8*)(Bs + (wn + ni * 16 + frow) * 64 + ph);
#pragma unroll
      for (int mi = 0; mi < 4; mi++)
#pragma unroll
        for (int ni = 0; ni < 4; ni++)
          acc[mi][ni] = __builtin_amdgcn_mfma_f32_16x16x32_bf16(af[mi], bf[ni], acc[mi][ni], 0, 0, 0);
    }
  }

  if (tid < 128) {
    int m = m0 + tid; int mm = m < cnt ? m : cnt - 1;
    tokLDS[tid] = list[so + mm];
    wLDS[tid] = wts[so + mm];
  }
  __syncthreads();

  const int colbase = n0 + wn + frow;
#pragma unroll
  for (int mi = 0; mi < 4; mi++) {
#pragma unroll
    for (int r = 0; r < 4; r++) {
      const int ml = wm + mi * 16 + quad * 4 + r;
      const int m = m0 + ml;
      if (m < cnt) {
        const int tok = tokLDS[ml];
        const float wv = wLDS[ml] * 0.25f;
        float* dst = out + (size_t)tok * HD + colbase;
#pragma unroll
        for (int ni = 0; ni < 4; ni++)
          atomicAdd(&dst[ni * 16], acc[mi][ni][r] * wv);
      }
    }
  }
}

// ---------------- workspace layout ----------------
#define OFF_XB   ((size_t)0)
#define OFF_W1   (OFF_XB + (size_t)T_TOK * HD * 2)
#define OFF_W2   (OFF_W1 + (size_t)NE * ID * HD * 2)
#define OFF_S    (OFF_W2 + (size_t)NE * ID * HD * 2)
#define OFF_RECE (OFF_S + (size_t)SROWS * ID * 2)
#define OFF_RECW (OFF_RECE + (size_t)T_TOK * 2 * 4)
#define OFF_LIST (OFF_RECW + (size_t)T_TOK * 2 * 4)
#define OFF_WTS  (OFF_LIST + (size_t)SROWS * 4)
#define OFF_CTRL (OFF_WTS + (size_t)SROWS * 4)
#define WS_NEED  (OFF_CTRL + 512)

extern "C" void kernel_launch(void* const* d_in, const int* in_sizes, int n_in,
                              void* d_out, int out_size, void* d_ws, size_t ws_size,
                              hipStream_t stream) {
  const float* x  = (const float*)d_in[0];
  const float* wr = (const float*)d_in[1];
  const float* wg = (const float*)d_in[2];
  const float* wu = (const float*)d_in[3];
  const float* wd = (const float*)d_in[4];
  float* out = (float*)d_out;

  if (ws_size < WS_NEED) return;

  char* ws = (char*)d_ws;
  unsigned short* xb   = (unsigned short*)(ws + OFF_XB);
  unsigned short* W1   = (unsigned short*)(ws + OFF_W1);   // wgT, then wdT
  unsigned short* W2   = (unsigned short*)(ws + OFF_W2);   // wuT
  unsigned short* sbuf = (unsigned short*)(ws + OFF_S);
  int*   rec_e = (int*)(ws + OFF_RECE);
  float* rec_w = (float*)(ws + OFF_RECW);
  int*   list  = (int*)(ws + OFF_LIST);
  float* wts   = (float*)(ws + OFF_WTS);
  int*   ctrl  = (int*)(ws + OFF_CTRL);

  hipMemsetAsync(ctrl, 0, 256, stream);
  hipMemsetAsync(out, 0, (size_t)T_TOK * HD * 4, stream);

  router_kernel<<<T_TOK / 4, 256, 0, stream>>>(x, wr, ctrl, rec_e, rec_w, xb);
  transpose_cvt_kernel<<<dim3(ID / 64, HD / 64, NE), 256, 0, stream>>>(wg, W1, HD, ID);
  transpose_cvt_kernel<<<dim3(ID / 64, HD / 64, NE), 256, 0, stream>>>(wu, W2, HD, ID);
  offsets_kernel<<<1, 64, 0, stream>>>(ctrl);
  scatter_kernel<<<T_TOK / 256, 256, 0, stream>>>(rec_e, rec_w, ctrl, list, wts);
  gemm1_kernel<<<GRID1, 256, 0, stream>>>(xb, W1, W2, ctrl, list, sbuf);
  transpose_cvt_kernel<<<dim3(HD / 64, ID / 64, NE), 256, 0, stream>>>(wd, W1, ID, HD);
  gemm2_kernel<<<GRID2, 256, 0, stream>>>(sbuf, W1, ctrl, list, wts, out);
}